// Round 6
// baseline (257.086 us; speedup 1.0000x reference)
//
#include <hip/hip_runtime.h>
#include <hip/hip_bf16.h>

// Problem: B=32, F_IN=64, F_OUT=64, D=512, K=64
// out[(b,o),d] = sum_{k,e} T[(b,o),(k,e)] * W[k,e,d],
// T[(b,o),(k,e)] = sum_i coeff[o,i,k] * x[b,i,e]
// R15: cross-step software pipeline. Step s computes T(s+1)->As[(s+1)&1]
// (independent of main(s) on As[s&1]/Bs[s&1]) -> ONE barrier/step, the
// T+main MFMA streams interleave freely. BK=32 (64 steps), ck-LDS removed
// (bc frags reg-loaded from L2-resident cb, 2-set parity dbuf), xe dbuf'd.
// LDS 80 KB (xe 2x16 + As 2x8 + Bs 2x16) -> 2 blocks/CU kept. Tile/waves/
// swizzle-law/epilogue identical to proven R9 family.

#define KK 32768

typedef __attribute__((ext_vector_type(8))) short bf16x8;
typedef __attribute__((ext_vector_type(4))) float f32x4;

__device__ __forceinline__ unsigned short f2bf(float f) {
  unsigned int u = __float_as_uint(f);
  return (unsigned short)((u + 0x7FFFu + ((u >> 16) & 1u)) >> 16);  // RNE
}

__device__ __forceinline__ unsigned int pkbf2(float a, float b) {
  __hip_bfloat162 h = __float22bfloat162_rn(make_float2(a, b));  // v_cvt_pk_bf16_f32
  return *(unsigned int*)&h;
}

__device__ __forceinline__ void gld16(void* lds, const void* g) {
  __builtin_amdgcn_global_load_lds((const __attribute__((address_space(1))) void*)g,
                                   (__attribute__((address_space(3))) void*)lds,
                                   16, 0, 0);
}

#define WAIT_VM0_LG0() asm volatile("s_waitcnt vmcnt(0) lgkmcnt(0)" ::: "memory")
#define WAIT_LG0()     asm volatile("s_waitcnt lgkmcnt(0)" ::: "memory")
#define BARRIER()      __builtin_amdgcn_s_barrier()
#define SCHEDB()       __builtin_amdgcn_sched_barrier(0)

// ---- merged preproc (R11, proven ~BW-bound). Blocks:
//   [0,2048):    W fp32 [64 k][512 e][512 d] -> WbT bf16 [512 d][k*512+e]
//   [2048,2176): x fp32 [32 b][64 i][512 e]  -> xT bf16 [b][e][i]
//   [2176,2240): coeff fp32 [64 o][64 i][64 k] -> cb bf16 [k][o*64+i]
__global__ __launch_bounds__(256) void prep_kern(const float* __restrict__ x,
                                                 const float* __restrict__ c,
                                                 const float* __restrict__ W,
                                                 unsigned short* __restrict__ xT,
                                                 unsigned short* __restrict__ cb,
                                                 unsigned short* __restrict__ WbT) {
  __shared__ float tile[64][133];            // 34 KB
  int bx = blockIdx.x;
  int t = threadIdx.x;
  if (bx < 2048) {
    int k = bx >> 5, et = (bx >> 2) & 7, dq = bx & 3;
    const float* src = W + ((size_t)k * 512 + (size_t)et * 64) * 512 + dq * 128;
    int rr = t >> 5, c4 = t & 31;
#pragma unroll
    for (int p = 0; p < 8; p++) {
      int e = p * 8 + rr;
      float4 v = *(const float4*)(src + (size_t)e * 512 + c4 * 4);
      *(float4*)&tile[e][c4 * 4] = v;
    }
    __syncthreads();
    int ch = t & 7, dr = t >> 3;
#pragma unroll
    for (int p = 0; p < 4; p++) {
      int d = p * 32 + dr, e0 = ch * 8;
      uint4 o4;
      o4.x = pkbf2(tile[e0 + 0][d], tile[e0 + 1][d]);
      o4.y = pkbf2(tile[e0 + 2][d], tile[e0 + 3][d]);
      o4.z = pkbf2(tile[e0 + 4][d], tile[e0 + 5][d]);
      o4.w = pkbf2(tile[e0 + 6][d], tile[e0 + 7][d]);
      *(uint4*)(WbT + (size_t)(dq * 128 + d) * KK + k * 512 + et * 64 + e0) = o4;
    }
  } else if (bx < 2176) {
    int bx2 = bx - 2048;
    int b = bx2 >> 2, ec = bx2 & 3;
    const float* src = x + (size_t)b * 32768 + ec * 128;
    int rr = t >> 5, c4 = t & 31;
#pragma unroll
    for (int p = 0; p < 8; p++) {
      int i = p * 8 + rr;
      float4 v = *(const float4*)(src + (size_t)i * 512 + c4 * 4);
      *(float4*)&tile[i][c4 * 4] = v;
    }
    __syncthreads();
    unsigned short* dst = xT + (size_t)b * 32768 + ec * 128 * 64;
    int ch = t & 7, er = t >> 3;
#pragma unroll
    for (int p = 0; p < 4; p++) {
      int e = p * 32 + er, i0 = ch * 8;
      uint4 o4;
      o4.x = pkbf2(tile[i0 + 0][e], tile[i0 + 1][e]);
      o4.y = pkbf2(tile[i0 + 2][e], tile[i0 + 3][e]);
      o4.z = pkbf2(tile[i0 + 4][e], tile[i0 + 5][e]);
      o4.w = pkbf2(tile[i0 + 6][e], tile[i0 + 7][e]);
      *(uint4*)(dst + e * 64 + i0) = o4;
    }
  } else {
    int rb = bx - 2176;
    unsigned short* lds = (unsigned short*)tile;
    const float* src = c + (size_t)rb * 4096;
#pragma unroll
    for (int j = 0; j < 16; j++) {
      int idx = j * 256 + t;
      int r = idx >> 6, k = idx & 63;
      lds[r * 66 + k] = f2bf(src[idx]);
    }
    __syncthreads();
#pragma unroll
    for (int j = 0; j < 16; j++) {
      int idx = j * 256 + t;
      int k = idx >> 6, r = idx & 63;
      cb[(size_t)k * 4096 + rb * 64 + r] = lds[r * 66 + k];
    }
  }
}

// ---- fused T+GEMM (R15): grid 512 = mt(16) x np(2) x ks(16); block-tile
// 128m x 256n, kk-chunk 2048 as 64 steps of BK=32: s = ec*8 + kw*2 + h.
// Per step (ONE barrier): issue B(s+1)/xe/bc(s+2) -> T(s+1) 8 MFMA ->
// As[(s+1)&1] writes -> main(s) 32 MFMA from As[s&1]/Bs[s&1] -> vm0+lg0+bar.
__global__ __launch_bounds__(256, 2) void fused_kern(const unsigned short* __restrict__ xT,
                                                     const unsigned short* __restrict__ cb,
                                                     const unsigned short* __restrict__ Bt,
                                                     float* __restrict__ out) {
  __shared__ unsigned short xe[2][8192];     // [b_l*64+e_l][i 64], 2 x 16 KB
  __shared__ unsigned short As[2][4096];     // [128 bo][32 e], 2 x 8 KB
  __shared__ unsigned short Bs[2][8192];     // [256 d][32 e], 2 x 16 KB
  int bx = blockIdx.x;                       // ks minor: mt-siblings co-XCD
  int ks = bx & 15, np = (bx >> 4) & 1, mt = bx >> 5;
  int m0 = mt * 128, n0 = np * 256, kw0 = ks * 4, b0 = mt * 2;
  int t = threadIdx.x;
  int wid = t >> 6, lane = t & 63, q = lane >> 4, l16 = lane & 15;
  int wmb = wid & 1;                         // m-half (= b index in T-phase)
  int wnh = wid >> 1;                        // n-half (= o-tile-pair in T-phase)
  int srow = t >> 3;                         // xe staging: 0..31 row-in-round
  int cg = (t & 7) ^ (srow & 7);             // xe source slot (8-slot law)
  int brow = t >> 2;                         // Bs staging: 0..63 row-in-round
  int cgb = (t & 3) ^ (brow & 3);            // Bs source slot (4-slot law)
  int o_[2] = { (wnh * 2 + 0) * 16 + l16, (wnh * 2 + 1) * 16 + l16 };

  bf16x8 bcS0[2][2], bcS1[2][2];             // bc reg dbuf (parity sets)

  // ---- prologue: xe[0](ec0), Bs[0](s=0), bc(0)->S0, bc(1)->S1
#pragma unroll
  for (int j = 0; j < 4; j++) {
    int row = j * 32 + srow;
    gld16((char*)xe[0] + (j * 256 + t) * 16,
          xT + (size_t)(b0 + (row >> 6)) * 32768 + (size_t)(row & 63) * 64 + cg * 8);
  }
#pragma unroll
  for (int j = 0; j < 4; j++) {
    int row = j * 64 + brow;
    gld16((char*)Bs[0] + (j * 256 + t) * 16,
          Bt + (size_t)(n0 + row) * KK + (size_t)kw0 * 512 + cgb * 8);
  }
  {                                          // kw(0)=kw(1)=0
    const unsigned short* cbb = cb + (size_t)kw0 * 4096;
#pragma unroll
    for (int otl = 0; otl < 2; otl++)
#pragma unroll
      for (int k2 = 0; k2 < 2; k2++) {
        bcS0[otl][k2] = *(const bf16x8*)(cbb + o_[otl] * 64 + k2 * 32 + q * 8);
        bcS1[otl][k2] = *(const bf16x8*)(cbb + o_[otl] * 64 + k2 * 32 + q * 8);
      }
  }
  WAIT_VM0_LG0(); BARRIER(); SCHEDB();
  // T(0) -> As[0]  (ec=0, h=0, uses bcS0)
  {
    bf16x8 axq[2][2];
#pragma unroll
    for (int e2 = 0; e2 < 2; e2++)
#pragma unroll
      for (int k2 = 0; k2 < 2; k2++) {
        int row = wmb * 64 + e2 * 16 + l16;
        axq[e2][k2] = *(const bf16x8*)(&xe[0][row * 64 + (((k2 * 4 + q) ^ (row & 7))) * 8]);
      }
    f32x4 td[2][2] = {};
#pragma unroll
    for (int e2 = 0; e2 < 2; e2++)
#pragma unroll
      for (int otl = 0; otl < 2; otl++)
#pragma unroll
        for (int k2 = 0; k2 < 2; k2++)
          td[e2][otl] = __builtin_amdgcn_mfma_f32_16x16x32_bf16(axq[e2][k2], bcS0[otl][k2],
                                                                td[e2][otl], 0, 0, 0);
#pragma unroll
    for (int e2 = 0; e2 < 2; e2++)
#pragma unroll
      for (int otl = 0; otl < 2; otl++) {
        int row = wmb * 64 + (wnh * 2 + otl) * 16 + l16;
        int c0 = e2 * 16 + q * 4;
        int phys = (((c0 >> 3) ^ (row & 3))) * 8 + (c0 & 7);
        uint2 v;
        v.x = pkbf2(td[e2][otl][0], td[e2][otl][1]);
        v.y = pkbf2(td[e2][otl][2], td[e2][otl][3]);
        *(uint2*)(&As[0][row * 32 + phys]) = v;
      }
  }
  WAIT_LG0(); BARRIER(); SCHEDB();

  f32x4 acc[4][8] = {};                      // wave 64m x 128n

  // step body: uses As[S&1]/Bs[S&1]; builds T(S+1); USE=bc(S+1), LOAD<-bc(S+2)
#define STEP_BODY(S, USE, LOAD)                                                          \
  do {                                                                                   \
    int sn = (S) + 1;                                                                    \
    int kwn = (sn >> 1) & 3, ecn = sn >> 3, hn = sn & 1;                                 \
    /* issue B(S+1) -> Bs[sn&1] (harmless OOB-pattern at S=63, never read) */            \
    {                                                                                    \
      size_t kkb = (size_t)(kw0 + kwn) * 512 + (size_t)ecn * 64 + hn * 32;               \
      _Pragma("unroll")                                                                  \
      for (int j = 0; j < 4; j++) {                                                      \
        int row = j * 64 + brow;                                                         \
        gld16((char*)Bs[sn & 1] + (j * 256 + t) * 16,                                    \
              Bt + (size_t)(n0 + row) * KK + kkb + cgb * 8);                             \
      }                                                                                  \
    }                                                                                    \
    /* xe staging once per ec (first step of ec), for ec+1 */                            \
    if (((S) & 7) == 0 && ((S) >> 3) < 7) {                                              \
      int ecs = ((S) >> 3) + 1;                                                          \
      _Pragma("unroll")                                                                  \
      for (int j = 0; j < 4; j++) {                                                      \
        int row = j * 32 + srow;                                                         \
        gld16((char*)xe[ecs & 1] + (j * 256 + t) * 16,                                   \
              xT + (size_t)(b0 + (row >> 6)) * 32768 +                                   \
                  (size_t)(ecs * 64 + (row & 63)) * 64 + cg * 8);                        \
      }                                                                                  \
    }                                                                                    \
    /* load bc(S+2) into LOAD set (regs; L2-resident cb) */                              \
    {                                                                                    \
      int kw2 = (((S) + 2) >> 1) & 3;                                                    \
      const unsigned short* cbb = cb + (size_t)(kw0 + kw2) * 4096;                       \
      _Pragma("unroll")                                                                  \
      for (int otl = 0; otl < 2; otl++)                                                  \
        _Pragma("unroll")                                                                \
        for (int k2 = 0; k2 < 2; k2++)                                                   \
          LOAD[otl][k2] = *(const bf16x8*)(cbb + o_[otl] * 64 + k2 * 32 + q * 8);        \
    }                                                                                    \
    /* T(S+1): independent of main(S); interleaves freely */                             \
    if ((S) < 63) {                                                                      \
      bf16x8 axq[2][2];                                                                  \
      _Pragma("unroll")                                                                  \
      for (int e2 = 0; e2 < 2; e2++)                                                     \
        _Pragma("unroll")                                                                \
        for (int k2 = 0; k2 < 2; k2++) {                                                 \
          int row = wmb * 64 + hn * 32 + e2 * 16 + l16;                                  \
          axq[e2][k2] =                                                                  \
              *(const bf16x8*)(&xe[ecn & 1][row * 64 + (((k2 * 4 + q) ^ (row & 7))) * 8]);\
        }                                                                                \
      f32x4 td[2][2] = {};                                                               \
      _Pragma("unroll")                                                                  \
      for (int e2 = 0; e2 < 2; e2++)                                                     \
        _Pragma("unroll")                                                                \
        for (int otl = 0; otl < 2; otl++)                                                \
          _Pragma("unroll")                                                              \
          for (int k2 = 0; k2 < 2; k2++)                                                 \
            td[e2][otl] = __builtin_amdgcn_mfma_f32_16x16x32_bf16(                       \
                axq[e2][k2], USE[otl][k2], td[e2][otl], 0, 0, 0);                        \
      _Pragma("unroll")                                                                  \
      for (int e2 = 0; e2 < 2; e2++)                                                     \
        _Pragma("unroll")                                                                \
        for (int otl = 0; otl < 2; otl++) {                                              \
          int row = wmb * 64 + (wnh * 2 + otl) * 16 + l16;                               \
          int c0 = e2 * 16 + q * 4;                                                      \
          int phys = (((c0 >> 3) ^ (row & 3))) * 8 + (c0 & 7);                           \
          uint2 v;                                                                       \
          v.x = pkbf2(td[e2][otl][0], td[e2][otl][1]);                                   \
          v.y = pkbf2(td[e2][otl][2], td[e2][otl][3]);                                   \
          *(uint2*)(&As[sn & 1][row * 32 + phys]) = v;                                   \
        }                                                                                \
    }                                                                                    \
    /* main(S): 32 MFMA from As[S&1]/Bs[S&1] */                                          \
    {                                                                                    \
      bf16x8 af[4], bfr[8];                                                              \
      _Pragma("unroll")                                                                  \
      for (int mf = 0; mf < 4; mf++) {                                                   \
        int row = wmb * 64 + mf * 16 + l16;                                              \
        af[mf] = *(const bf16x8*)(&As[(S) & 1][row * 32 + ((q ^ (row & 3))) * 8]);       \
      }                                                                                  \
      _Pragma("unroll")                                                                  \
      for (int nf = 0; nf < 8; nf++) {                                                   \
        int row = wnh * 128 + nf * 16 + l16;                                             \
        bfr[nf] = *(const bf16x8*)(&Bs[(S) & 1][row * 32 + ((q ^ (row & 3))) * 8]);      \
      }                                                                                  \
      __builtin_amdgcn_s_setprio(1);                                                     \
      _Pragma("unroll")                                                                  \
      for (int mf = 0; mf < 4; mf++)                                                     \
        _Pragma("unroll")                                                                \
        for (int nf = 0; nf < 8; nf++)                                                   \
          acc[mf][nf] = __builtin_amdgcn_mfma_f32_16x16x32_bf16(af[mf], bfr[nf],         \
                                                                acc[mf][nf], 0, 0, 0);   \
      __builtin_amdgcn_s_setprio(0);                                                     \
    }                                                                                    \
    WAIT_VM0_LG0(); BARRIER(); SCHEDB();                                                 \
  } while (0)

  int s = 0;
#pragma unroll 1
  for (int it = 0; it < 32; it++) {
    STEP_BODY(s, bcS1, bcS0); s++;           // even s: T(s+1) odd -> uses set1
    STEP_BODY(s, bcS0, bcS1); s++;           // odd  s: T(s+1) even -> uses set0
  }
#undef STEP_BODY

  // epilogue (R9 mapping): col = n0 + wnh*128 + nf*16 + l16
#pragma unroll
  for (int mf = 0; mf < 4; mf++)
#pragma unroll
    for (int nf = 0; nf < 8; nf++)
#pragma unroll
      for (int r = 0; r < 4; r++)
        atomicAdd(&out[(size_t)(m0 + wmb * 64 + mf * 16 + q * 4 + r) * 512
                       + n0 + wnh * 128 + nf * 16 + l16],
                  acc[mf][nf][r]);
}

// ---- fp32 fallback (only if ws too small)
__global__ __launch_bounds__(256) void fallback_kern(const float* __restrict__ x,
                                                     const float* __restrict__ W,
                                                     const float* __restrict__ coeff,
                                                     float* __restrict__ out) {
  __shared__ float ev[64][129];
  int b = blockIdx.x >> 6, k = blockIdx.x & 63;
  int t = threadIdx.x, dl = t & 127, half = t >> 7;
  const float* xb = x + (size_t)b * 64 * 512;
  const float* Wk = W + (size_t)k * 512 * 512;
  for (int dc = 0; dc < 4; dc++) {
    int d = dc * 128 + dl;
    for (int i = half * 32; i < half * 32 + 32; i++) {
      float acc = 0.f;
      const float* xr = xb + (size_t)i * 512;
#pragma unroll 4
      for (int e = 0; e < 512; e++) acc += xr[e] * Wk[(size_t)e * 512 + d];
      ev[i][dl] = acc;
    }
    __syncthreads();
    for (int o = half * 32; o < half * 32 + 32; o++) {
      float s = 0.f;
#pragma unroll 8
      for (int i = 0; i < 64; i++) s += coeff[((size_t)o * 64 + i) * 64 + k] * ev[i][dl];
      atomicAdd(&out[((size_t)(b * 64 + o)) * 512 + d], s);
    }
    __syncthreads();
  }
}

extern "C" void kernel_launch(void* const* d_in, const int* in_sizes, int n_in,
                              void* d_out, int out_size, void* d_ws, size_t ws_size,
                              hipStream_t stream) {
  const float* x = (const float*)d_in[0];
  const float* W = (const float*)d_in[1];
  const float* coeff = (const float*)d_in[2];
  float* out = (float*)d_out;
  const size_t OFF_XT = 33554432;            // WbT: 512*32768*2
  const size_t OFF_CB = OFF_XT + 2097152;    // xT : 32*512*64*2
  const size_t NEED = OFF_CB + 524288;       // cb : 64*64*64*2

  hipMemsetAsync(d_out, 0, (size_t)out_size * sizeof(float), stream);
  if (ws_size >= NEED) {
    unsigned short* WbT = (unsigned short*)d_ws;
    unsigned short* xT  = (unsigned short*)((char*)d_ws + OFF_XT);
    unsigned short* cb  = (unsigned short*)((char*)d_ws + OFF_CB);
    prep_kern<<<2240, 256, 0, stream>>>(x, coeff, W, xT, cb, WbT);
    fused_kern<<<512, 256, 0, stream>>>(xT, cb, WbT, out);
  } else {
    fallback_kern<<<2048, 256, 0, stream>>>(x, W, coeff, out);
  }
}

// Round 8
// 254.579 us; speedup vs baseline: 1.0098x; 1.0098x over previous
//
#include <hip/hip_runtime.h>
#include <hip/hip_bf16.h>

// Problem: B=32, F_IN=64, F_OUT=64, D=512, K=64
// out[(b,o),d] = sum_{k,e} T[(b,o),(k,e)] * W[k,e,d],
// T[(b,o),(k,e)] = sum_i coeff[o,i,k] * x[b,i,e]
// R17: occupancy attack. R13/R14-proven skeleton + swizzles kept verbatim;
// ck LDS removed (bc reg-loaded from L2-hot cb, R15-refchecked pattern,
// double-set alternation, prefetched 1 step ahead); np=2->4 so block =
// 128m x 128n, Bs single 16 KB. LDS 80->32 KB => grid 1024 at 4 blocks/CU
// (16 waves/CU, 2x occupancy). Wave tile 64x64 (acc[4][4]). T recompute x4
// (+20% MFMA) accepted: every schedule at 2 blocks/CU pinned at 124 us with
// all pipes <30% => latency-bound; TLP is the untouched axis.
// R16 lesson: cooperative launch fails under graph capture -> reverted to
// two plain launches.

#define KK 32768

typedef __attribute__((ext_vector_type(8))) short bf16x8;
typedef __attribute__((ext_vector_type(4))) float f32x4;

__device__ __forceinline__ unsigned short f2bf(float f) {
  unsigned int u = __float_as_uint(f);
  return (unsigned short)((u + 0x7FFFu + ((u >> 16) & 1u)) >> 16);  // RNE
}

__device__ __forceinline__ unsigned int pkbf2(float a, float b) {
  __hip_bfloat162 h = __float22bfloat162_rn(make_float2(a, b));  // v_cvt_pk_bf16_f32
  return *(unsigned int*)&h;
}

__device__ __forceinline__ void gld16(void* lds, const void* g) {
  __builtin_amdgcn_global_load_lds((const __attribute__((address_space(1))) void*)g,
                                   (__attribute__((address_space(3))) void*)lds,
                                   16, 0, 0);
}

#define WAIT_VM0_LG0() asm volatile("s_waitcnt vmcnt(0) lgkmcnt(0)" ::: "memory")
#define WAIT_VM4_LG0() asm volatile("s_waitcnt vmcnt(4) lgkmcnt(0)" ::: "memory")
#define WAIT_LG0()     asm volatile("s_waitcnt lgkmcnt(0)" ::: "memory")
#define BARRIER()      __builtin_amdgcn_s_barrier()
#define SCHEDB()       __builtin_amdgcn_sched_barrier(0)

// ---- merged preproc (R11, proven). Blocks:
//   [0,2048):    W fp32 [64 k][512 e][512 d] -> WbT bf16 [512 d][k*512+e]
//   [2048,2176): x fp32 [32 b][64 i][512 e]  -> xT bf16 [b][e][i]
//   [2176,2240): coeff fp32 [64 o][64 i][64 k] -> cb bf16 [k][o*64+i]
__global__ __launch_bounds__(256) void prep_kern(const float* __restrict__ x,
                                                 const float* __restrict__ c,
                                                 const float* __restrict__ W,
                                                 unsigned short* __restrict__ xT,
                                                 unsigned short* __restrict__ cb,
                                                 unsigned short* __restrict__ WbT) {
  __shared__ float tile[64][133];            // 34 KB
  int bx = blockIdx.x;
  int t = threadIdx.x;
  if (bx < 2048) {
    int k = bx >> 5, et = (bx >> 2) & 7, dq = bx & 3;
    const float* src = W + ((size_t)k * 512 + (size_t)et * 64) * 512 + dq * 128;
    int rr = t >> 5, c4 = t & 31;
#pragma unroll
    for (int p = 0; p < 8; p++) {
      int e = p * 8 + rr;
      *(float4*)&tile[e][c4 * 4] = *(const float4*)(src + (size_t)e * 512 + c4 * 4);
    }
    __syncthreads();
    int ch = t & 7, dr = t >> 3;
#pragma unroll
    for (int p = 0; p < 4; p++) {
      int d = p * 32 + dr, e0 = ch * 8;
      uint4 o4;
      o4.x = pkbf2(tile[e0 + 0][d], tile[e0 + 1][d]);
      o4.y = pkbf2(tile[e0 + 2][d], tile[e0 + 3][d]);
      o4.z = pkbf2(tile[e0 + 4][d], tile[e0 + 5][d]);
      o4.w = pkbf2(tile[e0 + 6][d], tile[e0 + 7][d]);
      *(uint4*)(WbT + (size_t)(dq * 128 + d) * KK + k * 512 + et * 64 + e0) = o4;
    }
  } else if (bx < 2176) {
    int bx2 = bx - 2048;
    int b = bx2 >> 2, ec = bx2 & 3;
    const float* src = x + (size_t)b * 32768 + ec * 128;
    int rr = t >> 5, c4 = t & 31;
#pragma unroll
    for (int p = 0; p < 8; p++) {
      int i = p * 8 + rr;
      *(float4*)&tile[i][c4 * 4] = *(const float4*)(src + (size_t)i * 512 + c4 * 4);
    }
    __syncthreads();
    unsigned short* dst = xT + (size_t)b * 32768 + ec * 128 * 64;
    int ch = t & 7, er = t >> 3;
#pragma unroll
    for (int p = 0; p < 4; p++) {
      int e = p * 32 + er, i0 = ch * 8;
      uint4 o4;
      o4.x = pkbf2(tile[i0 + 0][e], tile[i0 + 1][e]);
      o4.y = pkbf2(tile[i0 + 2][e], tile[i0 + 3][e]);
      o4.z = pkbf2(tile[i0 + 4][e], tile[i0 + 5][e]);
      o4.w = pkbf2(tile[i0 + 6][e], tile[i0 + 7][e]);
      *(uint4*)(dst + e * 64 + i0) = o4;
    }
  } else {
    int rb = bx - 2176;
    unsigned short* lds = (unsigned short*)tile;
    const float* src = c + (size_t)rb * 4096;
#pragma unroll
    for (int j = 0; j < 16; j++) {
      int idx = j * 256 + t;
      int r = idx >> 6, k = idx & 63;
      lds[r * 66 + k] = f2bf(src[idx]);
    }
    __syncthreads();
#pragma unroll
    for (int j = 0; j < 16; j++) {
      int idx = j * 256 + t;
      int k = idx >> 6, r = idx & 63;
      cb[(size_t)k * 4096 + rb * 64 + r] = lds[r * 66 + k];
    }
  }
}

// ---- fused T+GEMM (R17): grid 1024 = mt(16) x np(4) x ks(16); block-tile
// 128m x 128n, kk-slice 2048 (4 k-words x 8 ec of 64). 4 waves of 64m x 64n,
// 4 blocks/CU (32 KB LDS). Per step s (k=s&3, ec=s>>2):
// [k==0: vm0+bar -> ax extract] -> issue bc(s+1) regs -> T (bc(s) regs)
// -> [k==0: lg0+bar race fix] -> As write -> vm4+lg0+bar (drains Bs, keeps
// bc(s+1) flying) -> main 32 MFMA -> lg0+bar -> stage Bs(s+1) [+xe if next ec].
__global__ __launch_bounds__(256, 2) void fused_kern(const unsigned short* __restrict__ xT,
                                                     const unsigned short* __restrict__ cb,
                                                     const unsigned short* __restrict__ Bt,
                                                     float* __restrict__ out) {
  __shared__ unsigned short u[128 * 64];     // xe (per-ec) / As alias, 16 KB
  __shared__ unsigned short Bs[128 * 64];    // 128 d-rows x 64 kk, 16 KB
  int bx = blockIdx.x;                       // [mt:16][np:4][ks:16]; ks minor ->
  int ks = bx & 15, np = (bx >> 4) & 3, mt = bx >> 6;  // mt-siblings co-XCD
  int m0 = mt * 128, n0 = np * 128, kw0 = ks * 4, b0 = mt * 2;
  int t = threadIdx.x;
  int wid = t >> 6, lane = t & 63, q = lane >> 4, l16 = lane & 15;
  int wmb = wid & 1;                         // m-half (= b index in T-phase)
  int wnh = wid >> 1;                        // n-half (= o-tile-pair in T-phase)
  int srow = t >> 3;                         // 0..31 staging row
  int cgx = (t & 7) ^ (srow & 7);
  int o_[2] = { (wnh * 2 + 0) * 16 + l16, (wnh * 2 + 1) * 16 + l16 };

  bf16x8 bcA[2][2], bcB[2][2];               // bc reg double-set

  // ---- prologue: xe(ec=0) 4 + Bs(s=0) 4 (gld16) + bc(0)->A (regs)
#pragma unroll
  for (int j = 0; j < 4; j++) {
    int row = j * 32 + srow;
    gld16((char*)u + (j * 256 + t) * 16,
          xT + (size_t)(b0 + (row >> 6)) * 32768 + (size_t)(row & 63) * 64 + cgx * 8);
  }
#pragma unroll
  for (int j = 0; j < 4; j++) {
    int row = j * 32 + srow;
    gld16((char*)Bs + (j * 256 + t) * 16,
          Bt + (size_t)(n0 + row) * KK + (size_t)kw0 * 512 + cgx * 8);
  }
  {
    const unsigned short* cbb = cb + (size_t)kw0 * 4096;
#pragma unroll
    for (int otl = 0; otl < 2; otl++)
#pragma unroll
      for (int k2 = 0; k2 < 2; k2++)
        bcA[otl][k2] = *(const bf16x8*)(cbb + o_[otl] * 64 + k2 * 32 + q * 8);
  }
  f32x4 acc[4][4] = {};                      // wave 64m x 64n
  bf16x8 ax[4][2];                           // A[m=e][k=i] frags, held per ec

  // step body: T uses USE=bc(s); prefetch bc(s+1) into LOAD
#define STEP_BODY(S, USE, LOAD)                                                          \
  do {                                                                                   \
    int k_ = (S) & 3;                                                                    \
    f32x4 td[4][2];                                                                      \
    if (k_ == 0) {                                                                       \
      WAIT_VM0_LG0(); BARRIER(); SCHEDB();   /* xe+Bs+bc landed */                       \
      _Pragma("unroll")                                                                  \
      for (int et = 0; et < 4; et++)                                                     \
        _Pragma("unroll")                                                                \
        for (int k2 = 0; k2 < 2; k2++) {                                                 \
          int row = wmb * 64 + et * 16 + l16;                                            \
          ax[et][k2] = *(const bf16x8*)(u + row * 64 + (((k2 * 4 + q) ^ (row & 7))) * 8);\
        }                                                                                \
    }                                                                                    \
    /* prefetch bc(S+1) (S=31: kn=0, loaded but unused, in-bounds) */                    \
    {                                                                                    \
      int kn = ((S) + 1) & 3;                                                            \
      const unsigned short* cbb = cb + (size_t)(kw0 + kn) * 4096;                        \
      _Pragma("unroll")                                                                  \
      for (int otl = 0; otl < 2; otl++)                                                  \
        _Pragma("unroll")                                                                \
        for (int k2 = 0; k2 < 2; k2++)                                                   \
          LOAD[otl][k2] = *(const bf16x8*)(cbb + o_[otl] * 64 + k2 * 32 + q * 8);        \
    }                                                                                    \
    /* T-phase: D[m=e][n=o] over i=64 */                                                 \
    __builtin_amdgcn_s_setprio(1);                                                       \
    _Pragma("unroll")                                                                    \
    for (int et = 0; et < 4; et++)                                                       \
      _Pragma("unroll")                                                                  \
      for (int otl = 0; otl < 2; otl++) {                                                \
        td[et][otl] = (f32x4){0.f, 0.f, 0.f, 0.f};                                       \
        _Pragma("unroll")                                                                \
        for (int k2 = 0; k2 < 2; k2++)                                                   \
          td[et][otl] = __builtin_amdgcn_mfma_f32_16x16x32_bf16(ax[et][k2], USE[otl][k2],\
                                                                td[et][otl], 0, 0, 0);   \
      }                                                                                  \
    __builtin_amdgcn_s_setprio(0);                                                       \
    if (k_ == 0) { WAIT_LG0(); BARRIER(); SCHEDB(); }  /* R13 race fix: ax reads done */ \
    /* As write (alias u) */                                                             \
    _Pragma("unroll")                                                                    \
    for (int et = 0; et < 4; et++)                                                       \
      _Pragma("unroll")                                                                  \
      for (int otl = 0; otl < 2; otl++) {                                                \
        int row = wmb * 64 + (wnh * 2 + otl) * 16 + l16;                                 \
        int c0 = et * 16 + q * 4;                                                        \
        int phys = ((c0 >> 3) ^ (row & 7)) * 8 + (c0 & 7);                               \
        uint2 v;                                                                         \
        v.x = pkbf2(td[et][otl][0], td[et][otl][1]);                                     \
        v.y = pkbf2(td[et][otl][2], td[et][otl][3]);                                     \
        *(uint2*)(u + row * 64 + phys) = v;                                              \
      }                                                                                  \
    /* pre-main: drain Bs (oldest 4) + As writes; keep bc(S+1) flying */                 \
    WAIT_VM4_LG0(); BARRIER(); SCHEDB();                                                 \
    /* main: 32 MFMA, acc += As[wm..][kk] * Bs[wnh*64..][kk] */                          \
    _Pragma("unroll")                                                                    \
    for (int k2 = 0; k2 < 2; k2++) {                                                     \
      bf16x8 af[4], bfr[4];                                                              \
      _Pragma("unroll")                                                                  \
      for (int mf = 0; mf < 4; mf++) {                                                   \
        int row = wmb * 64 + mf * 16 + l16;                                              \
        af[mf] = *(const bf16x8*)(u + row * 64 + (((k2 * 4 + q) ^ (row & 7))) * 8);      \
      }                                                                                  \
      _Pragma("unroll")                                                                  \
      for (int nf = 0; nf < 4; nf++) {                                                   \
        int row = wnh * 64 + nf * 16 + l16;                                              \
        bfr[nf] = *(const bf16x8*)(Bs + row * 64 + (((k2 * 4 + q) ^ (row & 7))) * 8);    \
      }                                                                                  \
      __builtin_amdgcn_s_setprio(1);                                                     \
      _Pragma("unroll")                                                                  \
      for (int mf = 0; mf < 4; mf++)                                                     \
        _Pragma("unroll")                                                                \
        for (int nf = 0; nf < 4; nf++)                                                   \
          acc[mf][nf] = __builtin_amdgcn_mfma_f32_16x16x32_bf16(af[mf], bfr[nf],         \
                                                                acc[mf][nf], 0, 0, 0);   \
      __builtin_amdgcn_s_setprio(0);                                                     \
    }                                                                                    \
    /* B_C: main LDS reads drained -> u/Bs free for next staging */                      \
    WAIT_LG0(); BARRIER(); SCHEDB();                                                     \
    if ((S) < 31) {                                                                      \
      int sn = (S) + 1, kn = sn & 3, ecn = sn >> 2;                                      \
      _Pragma("unroll")                                                                  \
      for (int j = 0; j < 4; j++) {                                                      \
        int row = j * 32 + srow;                                                         \
        gld16((char*)Bs + (j * 256 + t) * 16,                                            \
              Bt + (size_t)(n0 + row) * KK + (size_t)(kw0 + kn) * 512 +                  \
                  (size_t)ecn * 64 + cgx * 8);                                           \
      }                                                                                  \
      if (kn == 0) {                                                                     \
        _Pragma("unroll")                                                                \
        for (int j = 0; j < 4; j++) {                                                    \
          int row = j * 32 + srow;                                                       \
          gld16((char*)u + (j * 256 + t) * 16,                                           \
                xT + (size_t)(b0 + (row >> 6)) * 32768 +                                 \
                    (size_t)(ecn * 64 + (row & 63)) * 64 + cgx * 8);                     \
        }                                                                                \
      }                                                                                  \
    }                                                                                    \
  } while (0)

  int s = 0;
#pragma unroll 1
  for (int it = 0; it < 16; it++) {
    STEP_BODY(s, bcA, bcB); s++;             // even s: bc(s) in A, prefetch -> B
    STEP_BODY(s, bcB, bcA); s++;             // odd  s: bc(s) in B, prefetch -> A
  }
#undef STEP_BODY

  // epilogue: col = n0 + wnh*64 + nf*16 + l16
#pragma unroll
  for (int mf = 0; mf < 4; mf++)
#pragma unroll
    for (int nf = 0; nf < 4; nf++)
#pragma unroll
      for (int r = 0; r < 4; r++)
        atomicAdd(&out[(size_t)(m0 + wmb * 64 + mf * 16 + q * 4 + r) * 512
                       + n0 + wnh * 64 + nf * 16 + l16],
                  acc[mf][nf][r]);
}

// ---- fp32 fallback (only if ws too small)
__global__ __launch_bounds__(256) void fallback_kern(const float* __restrict__ x,
                                                     const float* __restrict__ W,
                                                     const float* __restrict__ coeff,
                                                     float* __restrict__ out) {
  __shared__ float ev[64][129];
  int b = blockIdx.x >> 6, k = blockIdx.x & 63;
  int t = threadIdx.x, dl = t & 127, half = t >> 7;
  const float* xb = x + (size_t)b * 64 * 512;
  const float* Wk = W + (size_t)k * 512 * 512;
  for (int dc = 0; dc < 4; dc++) {
    int d = dc * 128 + dl;
    for (int i = half * 32; i < half * 32 + 32; i++) {
      float acc = 0.f;
      const float* xr = xb + (size_t)i * 512;
#pragma unroll 4
      for (int e = 0; e < 512; e++) acc += xr[e] * Wk[(size_t)e * 512 + d];
      ev[i][dl] = acc;
    }
    __syncthreads();
    for (int o = half * 32; o < half * 32 + 32; o++) {
      float s = 0.f;
#pragma unroll 8
      for (int i = 0; i < 64; i++) s += coeff[((size_t)o * 64 + i) * 64 + k] * ev[i][dl];
      atomicAdd(&out[((size_t)(b * 64 + o)) * 512 + d], s);
    }
    __syncthreads();
  }
}

extern "C" void kernel_launch(void* const* d_in, const int* in_sizes, int n_in,
                              void* d_out, int out_size, void* d_ws, size_t ws_size,
                              hipStream_t stream) {
  const float* x = (const float*)d_in[0];
  const float* W = (const float*)d_in[1];
  const float* coeff = (const float*)d_in[2];
  float* out = (float*)d_out;
  const size_t OFF_XT = 33554432;            // WbT: 512*32768*2
  const size_t OFF_CB = OFF_XT + 2097152;    // xT : 32*512*64*2
  const size_t NEED = OFF_CB + 524288;       // cb : 64*64*64*2

  hipMemsetAsync(d_out, 0, (size_t)out_size * sizeof(float), stream);
  if (ws_size >= NEED) {
    unsigned short* WbT = (unsigned short*)d_ws;
    unsigned short* xT  = (unsigned short*)((char*)d_ws + OFF_XT);
    unsigned short* cb  = (unsigned short*)((char*)d_ws + OFF_CB);
    prep_kern<<<2240, 256, 0, stream>>>(x, coeff, W, xT, cb, WbT);
    fused_kern<<<1024, 256, 0, stream>>>(xT, cb, WbT, out);
  } else {
    fallback_kern<<<2048, 256, 0, stream>>>(x, W, coeff, out);
  }
}

// Round 9
// 215.631 us; speedup vs baseline: 1.1923x; 1.1806x over previous
//
#include <hip/hip_runtime.h>
#include <hip/hip_bf16.h>

// Problem: B=32, F_IN=64, F_OUT=64, D=512, K=64
// out[(b,o),d] = sum_{k,e} T[(b,o),(k,e)] * W[k,e,d],
// T[(b,o),(k,e)] = sum_i coeff[o,i,k] * x[b,i,e]
// R18: consolidation. fused_kern = R13 exact (passed, 124 us — best of the
// 5-schedule family; R15/R17 post-mortems: wave = 252 unified regs -> hard
// 2 waves/SIMD; 2-phase sync structure is the ceiling). prep_kern gains a
// 4th branch zeroing `out` (128 blocks), deleting the hipMemsetAsync graph
// node (3 launches -> 2).

#define KK 32768

typedef __attribute__((ext_vector_type(8))) short bf16x8;
typedef __attribute__((ext_vector_type(4))) float f32x4;

__device__ __forceinline__ unsigned short f2bf(float f) {
  unsigned int u = __float_as_uint(f);
  return (unsigned short)((u + 0x7FFFu + ((u >> 16) & 1u)) >> 16);  // RNE
}

__device__ __forceinline__ unsigned int pkbf2(float a, float b) {
  __hip_bfloat162 h = __float22bfloat162_rn(make_float2(a, b));  // v_cvt_pk_bf16_f32
  return *(unsigned int*)&h;
}

__device__ __forceinline__ void gld16(void* lds, const void* g) {
  __builtin_amdgcn_global_load_lds((const __attribute__((address_space(1))) void*)g,
                                   (__attribute__((address_space(3))) void*)lds,
                                   16, 0, 0);
}

#define WAIT_VM0_LG0() asm volatile("s_waitcnt vmcnt(0) lgkmcnt(0)" ::: "memory")
#define WAIT_VM4()     asm volatile("s_waitcnt vmcnt(4)" ::: "memory")
#define WAIT_LG0()     asm volatile("s_waitcnt lgkmcnt(0)" ::: "memory")
#define BARRIER()      __builtin_amdgcn_s_barrier()
#define SCHEDB()       __builtin_amdgcn_sched_barrier(0)

// ---- merged preproc + out-zero. Blocks:
//   [0,2048):    W fp32 [64 k][512 e][512 d] -> WbT bf16 [512 d][k*512+e]
//   [2048,2176): x fp32 [32 b][64 i][512 e]  -> xT bf16 [b][e][i]
//   [2176,2240): coeff fp32 [64 o][64 i][64 k] -> cb bf16 [k][o*64+i]
//   [2240,2368): zero out (4 MB, 32 KB/block, float4 stores)
__global__ __launch_bounds__(256) void prep_kern(const float* __restrict__ x,
                                                 const float* __restrict__ c,
                                                 const float* __restrict__ W,
                                                 unsigned short* __restrict__ xT,
                                                 unsigned short* __restrict__ cb,
                                                 unsigned short* __restrict__ WbT,
                                                 float* __restrict__ out) {
  __shared__ float tile[64][133];            // 34 KB
  int bx = blockIdx.x;
  int t = threadIdx.x;
  if (bx < 2048) {
    int k = bx >> 5, et = (bx >> 2) & 7, dq = bx & 3;
    const float* src = W + ((size_t)k * 512 + (size_t)et * 64) * 512 + dq * 128;
    int rr = t >> 5, c4 = t & 31;
#pragma unroll
    for (int p = 0; p < 8; p++) {
      int e = p * 8 + rr;
      *(float4*)&tile[e][c4 * 4] = *(const float4*)(src + (size_t)e * 512 + c4 * 4);
    }
    __syncthreads();
    int ch = t & 7, dr = t >> 3;
#pragma unroll
    for (int p = 0; p < 4; p++) {
      int d = p * 32 + dr, e0 = ch * 8;
      uint4 o4;
      o4.x = pkbf2(tile[e0 + 0][d], tile[e0 + 1][d]);
      o4.y = pkbf2(tile[e0 + 2][d], tile[e0 + 3][d]);
      o4.z = pkbf2(tile[e0 + 4][d], tile[e0 + 5][d]);
      o4.w = pkbf2(tile[e0 + 6][d], tile[e0 + 7][d]);
      *(uint4*)(WbT + (size_t)(dq * 128 + d) * KK + k * 512 + et * 64 + e0) = o4;
    }
  } else if (bx < 2176) {
    int bx2 = bx - 2048;
    int b = bx2 >> 2, ec = bx2 & 3;
    const float* src = x + (size_t)b * 32768 + ec * 128;
    int rr = t >> 5, c4 = t & 31;
#pragma unroll
    for (int p = 0; p < 8; p++) {
      int i = p * 8 + rr;
      *(float4*)&tile[i][c4 * 4] = *(const float4*)(src + (size_t)i * 512 + c4 * 4);
    }
    __syncthreads();
    unsigned short* dst = xT + (size_t)b * 32768 + ec * 128 * 64;
    int ch = t & 7, er = t >> 3;
#pragma unroll
    for (int p = 0; p < 4; p++) {
      int e = p * 32 + er, i0 = ch * 8;
      uint4 o4;
      o4.x = pkbf2(tile[i0 + 0][e], tile[i0 + 1][e]);
      o4.y = pkbf2(tile[i0 + 2][e], tile[i0 + 3][e]);
      o4.z = pkbf2(tile[i0 + 4][e], tile[i0 + 5][e]);
      o4.w = pkbf2(tile[i0 + 6][e], tile[i0 + 7][e]);
      *(uint4*)(dst + e * 64 + i0) = o4;
    }
  } else if (bx < 2240) {
    int rb = bx - 2176;
    unsigned short* lds = (unsigned short*)tile;
    const float* src = c + (size_t)rb * 4096;
#pragma unroll
    for (int j = 0; j < 16; j++) {
      int idx = j * 256 + t;
      int r = idx >> 6, k = idx & 63;
      lds[r * 66 + k] = f2bf(src[idx]);
    }
    __syncthreads();
#pragma unroll
    for (int j = 0; j < 16; j++) {
      int idx = j * 256 + t;
      int k = idx >> 6, r = idx & 63;
      cb[(size_t)k * 4096 + rb * 64 + r] = lds[r * 66 + k];
    }
  } else {
    // zero out: 128 blocks x 32 KB (8192 floats); thread t: 8 x float4
    float* dst = out + (size_t)(bx - 2240) * 8192;
    float4 z = {0.f, 0.f, 0.f, 0.f};
#pragma unroll
    for (int j = 0; j < 8; j++)
      *(float4*)(dst + (size_t)j * 1024 + t * 4) = z;
  }
}

// ---- fused T+GEMM (R13, proven 124 us): grid 512 = mt(16) x np(2) x ks(16);
// block-tile 128m x 256n, kk-slice 2048. 4 waves, 2 blocks/CU (80 KB LDS).
// Per (ec,k): T-MFMA -> B_A (vmcnt0: drains h0 loads issued a full phase ago)
// -> issue h1 loads -> As write -> B_A2 (lgkm only) -> main h0
// -> B_B (vmcnt0: drains h1, had As+h0 phase to fly) + issue next h0 -> main h1.
__global__ __launch_bounds__(256, 2) void fused_kern(const unsigned short* __restrict__ xT,
                                                     const unsigned short* __restrict__ cb,
                                                     const unsigned short* __restrict__ Bt,
                                                     float* __restrict__ out) {
  __shared__ unsigned short u[128 * 64];     // xe (per-ec) / As alias, 16 KB
  __shared__ unsigned short Bs0[128 * 64];   // d-rows 0..127, 16 KB
  __shared__ unsigned short Bs1[128 * 64];   // d-rows 128..255, 16 KB
  __shared__ unsigned short ck[4 * 64 * 64]; // 32 KB (4 k-words, whole block)
  int bx = blockIdx.x;                       // ks minor: mt-siblings co-XCD
  int ks = bx & 15, np = (bx >> 4) & 1, mt = bx >> 5;
  int m0 = mt * 128, n0 = np * 256, kw0 = ks * 4, b0 = mt * 2;
  int t = threadIdx.x;
  int wid = t >> 6, lane = t & 63, q = lane >> 4, l16 = lane & 15;
  int wmb = wid & 1;                         // m-half (= b index in T-phase)
  int wnh = wid >> 1;                        // n-half (= o-tile-pair in T-phase)
  int srow = t >> 3;                         // 0..31 staging row
  int cg = (t & 7) ^ (srow & 7);
  // ---- prologue: ck (32 KB, 8 rounds) + Bs0 for s=0 h0 (4 rounds)
  {
    const unsigned short* gc = cb + (size_t)kw0 * 4096;
#pragma unroll
    for (int j = 0; j < 8; j++) {
      int row = j * 32 + srow;               // row = kj*64 + o; row&7 == o&7
      gld16((char*)ck + (j * 256 + t) * 16, gc + (size_t)row * 64 + cg * 8);
    }
    const unsigned short* gb = Bt + (size_t)n0 * KK + (size_t)kw0 * 512; // ec=0,k=0,h0
#pragma unroll
    for (int j = 0; j < 4; j++)
      gld16((char*)Bs0 + (j * 256 + t) * 16, gb + (size_t)(j * 32 + srow) * KK + cg * 8);
  }
  f32x4 acc[4][8] = {};                      // wave 64m x 128n (nf = h*4 + nfq)
  bf16x8 ax[4][2];                           // A[m=e][k=i] frags, held per ec
#pragma unroll 1
  for (int s = 0; s < 32; s++) {
    int k = s & 3, ec = s >> 2;
    f32x4 td[4][2];                          // [et][otl], D[m=e][n=o]
    const unsigned short* ckk = ck + k * 4096;
    if (k != 0) {
      // T-phase BEFORE B_A: overlaps h0 loads still in flight
      bf16x8 bc[2][2];
#pragma unroll
      for (int otl = 0; otl < 2; otl++)
#pragma unroll
        for (int k2 = 0; k2 < 2; k2++) {
          int o = (wnh * 2 + otl) * 16 + l16;
          int s2 = (k2 * 4 + q) ^ (o & 7);
          bc[otl][k2] = *(const bf16x8*)(ckk + o * 64 + s2 * 8);
        }
#pragma unroll
      for (int et = 0; et < 4; et++)
#pragma unroll
        for (int otl = 0; otl < 2; otl++) {
          td[et][otl] = (f32x4){0.f, 0.f, 0.f, 0.f};
#pragma unroll
          for (int k2 = 0; k2 < 2; k2++)
            td[et][otl] = __builtin_amdgcn_mfma_f32_16x16x32_bf16(ax[et][k2], bc[otl][k2],
                                                                  td[et][otl], 0, 0, 0);
        }
      // B_A: drains Bs0(s) loads (flew during h1(s-1)); all waves past As reads
      WAIT_VM0_LG0(); BARRIER(); SCHEDB();
      // issue h1 loads (Bs1 readers all past B_A)
      {
        const unsigned short* gb = Bt + (size_t)(n0 + 128) * KK
                                      + (size_t)(kw0 + k) * 512 + ec * 64;
#pragma unroll
        for (int j = 0; j < 4; j++)
          gld16((char*)Bs1 + (j * 256 + t) * 16, gb + (size_t)(j * 32 + srow) * KK + cg * 8);
      }
    } else {
      // B_A: drains Bs0(s) + (s=0: ck); all waves done with u (As of prev ec)
      WAIT_VM0_LG0(); BARRIER(); SCHEDB();
      // stage xe(ec) into u, then issue h1 loads
#pragma unroll
      for (int j = 0; j < 4; j++) {
        int row = j * 32 + srow;
        int bl = row >> 6, el = row & 63;
        gld16((char*)u + (j * 256 + t) * 16,
              xT + (size_t)(b0 + bl) * 32768 + (size_t)(ec * 64 + el) * 64 + cg * 8);
      }
      {
        const unsigned short* gb = Bt + (size_t)(n0 + 128) * KK
                                      + (size_t)kw0 * 512 + ec * 64;
#pragma unroll
        for (int j = 0; j < 4; j++)
          gld16((char*)Bs1 + (j * 256 + t) * 16, gb + (size_t)(j * 32 + srow) * KK + cg * 8);
      }
      WAIT_VM4(); BARRIER(); SCHEDB();       // xe ready (4 Bs1 loads remain in flight)
      // ax frags for this ec
#pragma unroll
      for (int et = 0; et < 4; et++)
#pragma unroll
        for (int k2 = 0; k2 < 2; k2++) {
          int row = wmb * 64 + et * 16 + l16;
          int s2 = (k2 * 4 + q) ^ (row & 7);
          ax[et][k2] = *(const bf16x8*)(u + row * 64 + s2 * 8);
        }
      // T-phase (k=0)
      bf16x8 bc[2][2];
#pragma unroll
      for (int otl = 0; otl < 2; otl++)
#pragma unroll
        for (int k2 = 0; k2 < 2; k2++) {
          int o = (wnh * 2 + otl) * 16 + l16;
          int s2 = (k2 * 4 + q) ^ (o & 7);
          bc[otl][k2] = *(const bf16x8*)(ckk + o * 64 + s2 * 8);
        }
#pragma unroll
      for (int et = 0; et < 4; et++)
#pragma unroll
        for (int otl = 0; otl < 2; otl++) {
          td[et][otl] = (f32x4){0.f, 0.f, 0.f, 0.f};
#pragma unroll
          for (int k2 = 0; k2 < 2; k2++)
            td[et][otl] = __builtin_amdgcn_mfma_f32_16x16x32_bf16(ax[et][k2], bc[otl][k2],
                                                                  td[et][otl], 0, 0, 0);
        }
      // RACE FIX (R13): all waves must finish their ax reads of u before ANY
      // wave overwrites u with As (waves 0/2 share rows 0..63, 1/3 share
      // 64..127). The 4 Bs1 gld16 stay in flight (lgkm-only wait).
      WAIT_LG0(); BARRIER(); SCHEDB();
    }
    // write As (alias u): row = wmb*64 + (wnh*2+otl)*16 + l16 (bo), col e
#pragma unroll
    for (int et = 0; et < 4; et++)
#pragma unroll
      for (int otl = 0; otl < 2; otl++) {
        int row = wmb * 64 + (wnh * 2 + otl) * 16 + l16;
        int c0 = et * 16 + q * 4;
        int phys = ((c0 >> 3) ^ (row & 7)) * 8 + (c0 & 7);
        uint2 v;
        v.x = pkbf2(td[et][otl][0], td[et][otl][1]);
        v.y = pkbf2(td[et][otl][2], td[et][otl][3]);
        *(uint2*)(u + row * 64 + phys) = v;
      }
    // B_A2: As visible; h1 loads stay in flight (lgkm only)
    WAIT_LG0(); BARRIER(); SCHEDB();
    // main h0: acc[.][0..3] += As * Bs0 (d-rows 0..127)
#pragma unroll
    for (int k2 = 0; k2 < 2; k2++) {
      bf16x8 af[4], bfr[4];
#pragma unroll
      for (int mf = 0; mf < 4; mf++) {
        int row = wmb * 64 + mf * 16 + l16;
        af[mf] = *(const bf16x8*)(u + row * 64 + (((k2 * 4 + q) ^ (row & 7))) * 8);
      }
#pragma unroll
      for (int nf = 0; nf < 4; nf++) {
        int row = wnh * 64 + nf * 16 + l16;
        bfr[nf] = *(const bf16x8*)(Bs0 + row * 64 + (((k2 * 4 + q) ^ (row & 7))) * 8);
      }
      __builtin_amdgcn_s_setprio(1);
#pragma unroll
      for (int mf = 0; mf < 4; mf++)
#pragma unroll
        for (int nf = 0; nf < 4; nf++)
          acc[mf][nf] = __builtin_amdgcn_mfma_f32_16x16x32_bf16(af[mf], bfr[nf],
                                                                acc[mf][nf], 0, 0, 0);
      __builtin_amdgcn_s_setprio(0);
    }
    // B_B: drains h1 loads (flew during As+h0); Bs0 free for next h0
    WAIT_VM0_LG0(); BARRIER(); SCHEDB();
    if (s < 31) {                            // issue next step's h0 loads
      int sn = s + 1, kn = sn & 3, ecn = sn >> 2;
      const unsigned short* gb = Bt + (size_t)n0 * KK
                                    + (size_t)(kw0 + kn) * 512 + ecn * 64;
#pragma unroll
      for (int j = 0; j < 4; j++)
        gld16((char*)Bs0 + (j * 256 + t) * 16, gb + (size_t)(j * 32 + srow) * KK + cg * 8);
    }
    // main h1: acc[.][4..7] += As * Bs1 (d-rows 128..255)
#pragma unroll
    for (int k2 = 0; k2 < 2; k2++) {
      bf16x8 af[4], bfr[4];
#pragma unroll
      for (int mf = 0; mf < 4; mf++) {
        int row = wmb * 64 + mf * 16 + l16;
        af[mf] = *(const bf16x8*)(u + row * 64 + (((k2 * 4 + q) ^ (row & 7))) * 8);
      }
#pragma unroll
      for (int nf = 0; nf < 4; nf++) {
        int row = wnh * 64 + nf * 16 + l16;
        bfr[nf] = *(const bf16x8*)(Bs1 + row * 64 + (((k2 * 4 + q) ^ (row & 7))) * 8);
      }
      __builtin_amdgcn_s_setprio(1);
#pragma unroll
      for (int mf = 0; mf < 4; mf++)
#pragma unroll
        for (int nf = 0; nf < 4; nf++)
          acc[mf][4 + nf] = __builtin_amdgcn_mfma_f32_16x16x32_bf16(af[mf], bfr[nf],
                                                                    acc[mf][4 + nf], 0, 0, 0);
      __builtin_amdgcn_s_setprio(0);
    }
  }
  // epilogue: n-col = n0 + h*128 + wnh*64 + nfq*16 + l16
#pragma unroll
  for (int mf = 0; mf < 4; mf++)
#pragma unroll
    for (int nf = 0; nf < 8; nf++) {
      int col = n0 + (nf >> 2) * 128 + wnh * 64 + (nf & 3) * 16 + l16;
#pragma unroll
      for (int r = 0; r < 4; r++)
        atomicAdd(&out[(size_t)(m0 + wmb * 64 + mf * 16 + q * 4 + r) * 512 + col],
                  acc[mf][nf][r]);
    }
}

// ---- fp32 fallback (only if ws too small)
__global__ __launch_bounds__(256) void fallback_kern(const float* __restrict__ x,
                                                     const float* __restrict__ W,
                                                     const float* __restrict__ coeff,
                                                     float* __restrict__ out) {
  __shared__ float ev[64][129];
  int b = blockIdx.x >> 6, k = blockIdx.x & 63;
  int t = threadIdx.x, dl = t & 127, half = t >> 7;
  const float* xb = x + (size_t)b * 64 * 512;
  const float* Wk = W + (size_t)k * 512 * 512;
  for (int dc = 0; dc < 4; dc++) {
    int d = dc * 128 + dl;
    for (int i = half * 32; i < half * 32 + 32; i++) {
      float acc = 0.f;
      const float* xr = xb + (size_t)i * 512;
#pragma unroll 4
      for (int e = 0; e < 512; e++) acc += xr[e] * Wk[(size_t)e * 512 + d];
      ev[i][dl] = acc;
    }
    __syncthreads();
    for (int o = half * 32; o < half * 32 + 32; o++) {
      float s = 0.f;
#pragma unroll 8
      for (int i = 0; i < 64; i++) s += coeff[((size_t)o * 64 + i) * 64 + k] * ev[i][dl];
      atomicAdd(&out[((size_t)(b * 64 + o)) * 512 + d], s);
    }
    __syncthreads();
  }
}

extern "C" void kernel_launch(void* const* d_in, const int* in_sizes, int n_in,
                              void* d_out, int out_size, void* d_ws, size_t ws_size,
                              hipStream_t stream) {
  const float* x = (const float*)d_in[0];
  const float* W = (const float*)d_in[1];
  const float* coeff = (const float*)d_in[2];
  float* out = (float*)d_out;
  const size_t OFF_XT = 33554432;            // WbT: 512*32768*2
  const size_t OFF_CB = OFF_XT + 2097152;    // xT : 32*512*64*2
  const size_t NEED = OFF_CB + 524288;       // cb : 64*64*64*2

  if (ws_size >= NEED) {
    unsigned short* WbT = (unsigned short*)d_ws;
    unsigned short* xT  = (unsigned short*)((char*)d_ws + OFF_XT);
    unsigned short* cb  = (unsigned short*)((char*)d_ws + OFF_CB);
    prep_kern<<<2368, 256, 0, stream>>>(x, coeff, W, xT, cb, WbT, out);
    fused_kern<<<512, 256, 0, stream>>>(xT, cb, WbT, out);
  } else {
    hipMemsetAsync(d_out, 0, (size_t)out_size * sizeof(float), stream);
    fallback_kern<<<2048, 256, 0, stream>>>(x, W, coeff, out);
  }
}